// Round 1
// baseline (1872.721 us; speedup 1.0000x reference)
//
#include <hip/hip_runtime.h>
#include <hip/hip_bf16.h>

// Problem constants: B=4, S=2048, E=1024, H=16, DH=64. causal==1 always.
typedef __bf16 bf16;
typedef __bf16 bf16x4 __attribute__((ext_vector_type(4)));
typedef __bf16 bf16x8 __attribute__((ext_vector_type(8)));
typedef float f32x4 __attribute__((ext_vector_type(4)));

constexpr int Bc = 4, Sc = 2048, Ec = 1024, Hc = 16, DHc = 64;
constexpr int MBS = Bc * Sc;              // 8192 rows for all projections
constexpr size_t NE = (size_t)MBS * Ec;   // 8,388,608 elements

// ---------------------------------------------------------------------------
// GEMM (B-transposed): C[m,n] = sum_k A[m,k] * W[n,k] + bias[n]
// M=8192, N=1024, K=1024, all leading dims 1024. 128x128 tile, BK=32,
// 4 waves in 2x2, each wave 4x4 grid of 16x16x32 bf16 MFMA.
// AT = float (convert to bf16 in staging) or __bf16. OUT_BF16 selects C dtype.
// ---------------------------------------------------------------------------
template<typename AT, bool OUT_BF16>
__global__ __launch_bounds__(256) void gemm_bt_kernel(
    const AT* __restrict__ A, const float* __restrict__ W,
    const float* __restrict__ bias, void* __restrict__ Cout)
{
  __shared__ bf16 As[128][40];  // +8 pad: 80B rows -> 2-way banks (free)
  __shared__ bf16 Ws[128][40];
  const int tid  = threadIdx.x;
  const int wave = tid >> 6, lane = tid & 63;
  const int quad = lane >> 4, l16 = lane & 15;
  const int wm = (wave & 1) * 64, wn = (wave >> 1) * 64;
  const int m0 = blockIdx.y * 128, n0 = blockIdx.x * 128;
  f32x4 acc[4][4] = {};

  for (int k0 = 0; k0 < 1024; k0 += 32) {
    __syncthreads();
    if constexpr (sizeof(AT) == 4) {
      const int r = tid >> 3, c = (tid & 7) * 4;
#pragma unroll
      for (int p = 0; p < 4; ++p) {
        const float4 v = *(const float4*)&A[(size_t)(m0 + r + 32 * p) * 1024 + k0 + c];
        bf16x4 bv = { (bf16)v.x, (bf16)v.y, (bf16)v.z, (bf16)v.w };
        *(bf16x4*)&As[r + 32 * p][c] = bv;
      }
    } else {
      const int r = tid >> 1, c = (tid & 1) * 16;
      const uint4 v0 = *(const uint4*)&A[(size_t)(m0 + r) * 1024 + k0 + c];
      const uint4 v1 = *(const uint4*)&A[(size_t)(m0 + r) * 1024 + k0 + c + 8];
      *(uint4*)&As[r][c]     = v0;
      *(uint4*)&As[r][c + 8] = v1;
    }
    {
      const int r = tid >> 3, c = (tid & 7) * 4;
#pragma unroll
      for (int p = 0; p < 4; ++p) {
        const float4 v = *(const float4*)&W[(size_t)(n0 + r + 32 * p) * 1024 + k0 + c];
        bf16x4 bv = { (bf16)v.x, (bf16)v.y, (bf16)v.z, (bf16)v.w };
        *(bf16x4*)&Ws[r + 32 * p][c] = bv;
      }
    }
    __syncthreads();
    bf16x8 af[4], bg[4];
#pragma unroll
    for (int i = 0; i < 4; ++i)
      af[i] = *(const bf16x8*)&As[wm + i * 16 + l16][quad * 8];
#pragma unroll
    for (int j = 0; j < 4; ++j)
      bg[j] = *(const bf16x8*)&Ws[wn + j * 16 + l16][quad * 8];
#pragma unroll
    for (int i = 0; i < 4; ++i)
#pragma unroll
      for (int j = 0; j < 4; ++j)
        acc[i][j] = __builtin_amdgcn_mfma_f32_16x16x32_bf16(af[i], bg[j], acc[i][j], 0, 0, 0);
  }

#pragma unroll
  for (int j = 0; j < 4; ++j) {
    const int col = n0 + wn + j * 16 + l16;
    const float bv = bias[col];
#pragma unroll
    for (int i = 0; i < 4; ++i) {
      const int rowb = m0 + wm + i * 16 + quad * 4;
#pragma unroll
      for (int r = 0; r < 4; ++r) {
        const float v = acc[i][j][r] + bv;
        if constexpr (OUT_BF16)
          ((bf16*)Cout)[(size_t)(rowb + r) * 1024 + col] = (bf16)v;
        else
          ((float*)Cout)[(size_t)(rowb + r) * 1024 + col] = v;
      }
    }
  }
}

// ---------------------------------------------------------------------------
// Scores: per (b,h), 128x128 tile of Q_h @ K_h^T * 0.125, causal-masked to 0.
// Tiles entirely above the diagonal just write zeros (covers 0xAA poison).
// ---------------------------------------------------------------------------
__global__ __launch_bounds__(256) void scores_kernel(
    const bf16* __restrict__ Qp, const bf16* __restrict__ Kp,
    float* __restrict__ attn)
{
  const int tc = blockIdx.x, tr = blockIdx.y, bh = blockIdx.z;
  const int row0 = tr * 128, col0 = tc * 128;
  float* __restrict__ out = attn + (size_t)bh * Sc * Sc;
  const int tid = threadIdx.x;

  if (tc > tr) {  // fully masked tile -> zeros
    const int r = tid >> 1, cb = (tid & 1) * 64;
    const float4 z = {0.f, 0.f, 0.f, 0.f};
#pragma unroll
    for (int q = 0; q < 16; ++q)
      *(float4*)&out[(size_t)(row0 + r) * Sc + col0 + cb + q * 4] = z;
    return;
  }

  const int b = bh >> 4, h = bh & 15;
  const size_t hoff = (size_t)b * Sc * Ec + (size_t)h * 64;
  __shared__ bf16 Qs[128][72];  // 64 cols + 8 pad (144B rows, 16B aligned)
  __shared__ bf16 Ks[128][72];
#pragma unroll
  for (int p = 0; p < 4; ++p) {
    const int c = tid + 256 * p;
    const int r = c >> 3, ch = (c & 7) * 8;
    *(uint4*)&Qs[r][ch] = *(const uint4*)&Qp[hoff + (size_t)(row0 + r) * Ec + ch];
    *(uint4*)&Ks[r][ch] = *(const uint4*)&Kp[hoff + (size_t)(col0 + r) * Ec + ch];
  }
  __syncthreads();

  const int wave = tid >> 6, lane = tid & 63;
  const int quad = lane >> 4, l16 = lane & 15;
  const int wm = (wave & 1) * 64, wn = (wave >> 1) * 64;
  f32x4 acc[4][4] = {};
#pragma unroll
  for (int kk = 0; kk < 2; ++kk) {
    bf16x8 af[4], bg[4];
#pragma unroll
    for (int i = 0; i < 4; ++i)
      af[i] = *(const bf16x8*)&Qs[wm + i * 16 + l16][kk * 32 + quad * 8];
#pragma unroll
    for (int j = 0; j < 4; ++j)
      bg[j] = *(const bf16x8*)&Ks[wn + j * 16 + l16][kk * 32 + quad * 8];
#pragma unroll
    for (int i = 0; i < 4; ++i)
#pragma unroll
      for (int j = 0; j < 4; ++j)
        acc[i][j] = __builtin_amdgcn_mfma_f32_16x16x32_bf16(af[i], bg[j], acc[i][j], 0, 0, 0);
  }

#pragma unroll
  for (int i = 0; i < 4; ++i) {
    const int rowb = row0 + wm + i * 16 + quad * 4;
#pragma unroll
    for (int j = 0; j < 4; ++j) {
      const int col = col0 + wn + j * 16 + l16;
#pragma unroll
      for (int r = 0; r < 4; ++r) {
        const int row = rowb + r;
        float v = acc[i][j][r] * 0.125f;  // 1/sqrt(64)
        if (col > row) v = 0.f;           // only possible when tc == tr
        out[(size_t)row * Sc + col] = v;
      }
    }
  }
}

// ---------------------------------------------------------------------------
// Row softmax over causal prefix len = s+1, in place. Masked suffix stays 0.
// ---------------------------------------------------------------------------
__global__ __launch_bounds__(256) void softmax_kernel(float* __restrict__ attn)
{
  const int s = blockIdx.x, bh = blockIdx.y;
  float* __restrict__ row = attn + ((size_t)bh * Sc + s) * Sc;
  const int len = s + 1;
  const int tid = threadIdx.x;
  float vals[8];
  float mx = -3.4e38f;
#pragma unroll
  for (int it = 0; it < 8; ++it) {
    const int i = tid + it * 256;
    const float v = (i < len) ? row[i] : -3.4e38f;
    vals[it] = v;
    mx = fmaxf(mx, v);
  }
  __shared__ float red[4];
#pragma unroll
  for (int off = 32; off > 0; off >>= 1)
    mx = fmaxf(mx, __shfl_down(mx, off, 64));
  const int wave = tid >> 6, lane = tid & 63;
  if (lane == 0) red[wave] = mx;
  __syncthreads();
  mx = fmaxf(fmaxf(red[0], red[1]), fmaxf(red[2], red[3]));

  float sum = 0.f;
#pragma unroll
  for (int it = 0; it < 8; ++it) {
    const int i = tid + it * 256;
    if (i < len) { const float e = __expf(vals[it] - mx); vals[it] = e; sum += e; }
  }
#pragma unroll
  for (int off = 32; off > 0; off >>= 1)
    sum += __shfl_down(sum, off, 64);
  __syncthreads();
  if (lane == 0) red[wave] = sum;
  __syncthreads();
  sum = red[0] + red[1] + red[2] + red[3];
  const float inv = 1.f / sum;
#pragma unroll
  for (int it = 0; it < 8; ++it) {
    const int i = tid + it * 256;
    if (i < len) row[i] = vals[it] * inv;
  }
}

// ---------------------------------------------------------------------------
// PV: per (b,h), O_h[row0..row0+127][0..63] = attn_tile @ V_h.
// attn is fp32 (converted to bf16 in staging); V transposed through LDS.
// Causal: columns > row0+127 are all zero -> K loop stops at row0+128.
// ---------------------------------------------------------------------------
__global__ __launch_bounds__(256) void pv_kernel(
    const float* __restrict__ attn, const bf16* __restrict__ Vp,
    bf16* __restrict__ Op)
{
  const int mt = blockIdx.x, bh = blockIdx.y;
  const int b = bh >> 4, h = bh & 15;
  const int row0 = mt * 128;
  const float* __restrict__ P = attn + (size_t)bh * Sc * Sc;
  const bf16* __restrict__ Vh = Vp + (size_t)b * Sc * Ec + (size_t)h * 64;
  bf16* __restrict__ Oh = Op + (size_t)b * Sc * Ec + (size_t)h * 64;

  __shared__ bf16 Ps[128][40];
  __shared__ bf16 Vt[64][40];  // V transposed: Vt[n][k]
  const int tid  = threadIdx.x;
  const int wave = tid >> 6, lane = tid & 63;
  const int quad = lane >> 4, l16 = lane & 15;
  const int wm = (wave & 1) * 64, wn = (wave >> 1) * 32;
  f32x4 acc[4][2] = {};
  const int kend = row0 + 128;

  for (int k0 = 0; k0 < kend; k0 += 32) {
    __syncthreads();
    {
      const int r = tid >> 3, c = (tid & 7) * 4;
#pragma unroll
      for (int p = 0; p < 4; ++p) {
        const float4 v = *(const float4*)&P[(size_t)(row0 + r + 32 * p) * Sc + k0 + c];
        bf16x4 bv = { (bf16)v.x, (bf16)v.y, (bf16)v.z, (bf16)v.w };
        *(bf16x4*)&Ps[r + 32 * p][c] = bv;
      }
    }
    {
      const int kk = tid >> 3, nn = (tid & 7) * 8;
      const uint4 raw = *(const uint4*)&Vh[(size_t)(k0 + kk) * Ec + nn];
      const bf16* pv = reinterpret_cast<const bf16*>(&raw);
#pragma unroll
      for (int jj = 0; jj < 8; ++jj) Vt[nn + jj][kk] = pv[jj];
    }
    __syncthreads();
    bf16x8 af[4], bg[2];
#pragma unroll
    for (int i = 0; i < 4; ++i)
      af[i] = *(const bf16x8*)&Ps[wm + i * 16 + l16][quad * 8];
#pragma unroll
    for (int j = 0; j < 2; ++j)
      bg[j] = *(const bf16x8*)&Vt[wn + j * 16 + l16][quad * 8];
#pragma unroll
    for (int i = 0; i < 4; ++i)
#pragma unroll
      for (int j = 0; j < 2; ++j)
        acc[i][j] = __builtin_amdgcn_mfma_f32_16x16x32_bf16(af[i], bg[j], acc[i][j], 0, 0, 0);
  }

#pragma unroll
  for (int j = 0; j < 2; ++j) {
    const int col = wn + j * 16 + l16;
#pragma unroll
    for (int i = 0; i < 4; ++i) {
      const int rowb = row0 + wm + i * 16 + quad * 4;
#pragma unroll
      for (int r = 0; r < 4; ++r)
        Oh[(size_t)(rowb + r) * Ec + col] = (bf16)acc[i][j][r];
    }
  }
}

// ---------------------------------------------------------------------------
extern "C" void kernel_launch(void* const* d_in, const int* in_sizes, int n_in,
                              void* d_out, int out_size, void* d_ws, size_t ws_size,
                              hipStream_t stream) {
  (void)in_sizes; (void)n_in; (void)out_size; (void)ws_size;
  const float* q  = (const float*)d_in[0];
  const float* k  = (const float*)d_in[1];
  const float* v  = (const float*)d_in[2];
  const float* wq = (const float*)d_in[3];
  const float* bq = (const float*)d_in[4];
  const float* wk = (const float*)d_in[5];
  const float* bk = (const float*)d_in[6];
  const float* wv = (const float*)d_in[7];
  const float* bv = (const float*)d_in[8];
  const float* wo = (const float*)d_in[9];
  const float* bo = (const float*)d_in[10];
  // causal flag (d_in[11]) is always 1 for this problem; hardcoded.

  float* out  = (float*)d_out;
  float* attn = out + NE;  // [B,H,S,S] fp32, 268,435,456 elements

  bf16* wsQ = (bf16*)d_ws;           // [8192,1024] bf16 each
  bf16* wsK = wsQ + NE;
  bf16* wsV = wsK + NE;
  bf16* wsO = wsV + NE;

  const dim3 gP(8, 64);  // N/128, M/128
  gemm_bt_kernel<float, true><<<gP, 256, 0, stream>>>(q, wq, bq, wsQ);
  gemm_bt_kernel<float, true><<<gP, 256, 0, stream>>>(k, wk, bk, wsK);
  gemm_bt_kernel<float, true><<<gP, 256, 0, stream>>>(v, wv, bv, wsV);

  scores_kernel<<<dim3(16, 16, 64), 256, 0, stream>>>(wsQ, wsK, attn);
  softmax_kernel<<<dim3(2048, 64), 256, 0, stream>>>(attn);
  pv_kernel<<<dim3(16, 64), 256, 0, stream>>>(attn, wsV, wsO);

  gemm_bt_kernel<__bf16, false><<<gP, 256, 0, stream>>>(wsO, wo, bo, out);
}